// Round 9
// baseline (158.792 us; speedup 1.0000x reference)
//
#include <hip/hip_runtime.h>

#define NR    8192
#define ALPHA 0.2f
#define NB    256

__device__ inline unsigned enc_f32(float f) {
    unsigned u = __float_as_uint(f);
    return (u & 0x80000000u) ? ~u : (u | 0x80000000u);
}
__device__ inline float dec_f32(unsigned u) {
    return __uint_as_float((u & 0x80000000u) ? (u ^ 0x80000000u) : ~u);
}

// Hand-rolled grid barrier: ONE monotonic counter, rising targets.
__device__ inline void gbar(unsigned* counter, unsigned target) {
    __syncthreads();
    if (threadIdx.x == 0) {
        __threadfence();   // release
        __hip_atomic_fetch_add(counter, 1u, __ATOMIC_RELAXED, __HIP_MEMORY_SCOPE_AGENT);
        while (__hip_atomic_load(counter, __ATOMIC_RELAXED, __HIP_MEMORY_SCOPE_AGENT) < target)
            __builtin_amdgcn_s_sleep(2);
        __threadfence();   // acquire
    }
    __syncthreads();
}

// ---------- Phase A: H = X@W, f1, f2 -> enc key (32 rows/block, 256 blocks) ----------
__device__ inline void phaseA(int tid, int bid,
    const float* __restrict__ X, const float* __restrict__ W, const float* __restrict__ aa,
    float* __restrict__ H, float* __restrict__ F1, unsigned* __restrict__ ENC,
    float* __restrict__ xs, float* __restrict__ part)
{
    const int w = tid >> 6, c = tid & 63;
    const int R0 = bid * 32;
    float Wreg[32];
#pragma unroll
    for (int e = 0; e < 32; ++e) Wreg[e] = W[(w * 32 + e) * 64 + c];
    {
        const float4* X4 = (const float4*)(X + R0 * 128);
        float4* xs4 = (float4*)xs;
#pragma unroll
        for (int q = 0; q < 4; ++q) xs4[q * 256 + tid] = X4[q * 256 + tid];
    }
    __syncthreads();

    for (int r = 0; r < 32; ++r) {
        const float4* xr4 = (const float4*)&xs[r * 128 + w * 32];
        float acc = 0.f;
#pragma unroll
        for (int e = 0; e < 8; ++e) {
            float4 xv = xr4[e];
            acc = fmaf(xv.x, Wreg[e * 4 + 0], acc);
            acc = fmaf(xv.y, Wreg[e * 4 + 1], acc);
            acc = fmaf(xv.z, Wreg[e * 4 + 2], acc);
            acc = fmaf(xv.w, Wreg[e * 4 + 3], acc);
        }
        part[(r * 4 + w) * 64 + c] = acc;
    }
    __syncthreads();

    const float a1 = aa[c], a2 = aa[64 + c];
    for (int rr = 0; rr < 8; ++rr) {
        const int r = w * 8 + rr;
        const int i = R0 + r;
        float h = part[(r * 4 + 0) * 64 + c] + part[(r * 4 + 1) * 64 + c]
                + part[(r * 4 + 2) * 64 + c] + part[(r * 4 + 3) * 64 + c];
        H[i * 64 + c] = h;
        float v1 = h * a1, v2 = h * a2;
#pragma unroll
        for (int m = 32; m >= 1; m >>= 1) {
            v1 += __shfl_xor(v1, m, 64);
            v2 += __shfl_xor(v2, m, 64);
        }
        if (c == 0) { F1[i] = v1; ENC[i] = enc_f32(v2); }
    }
}

// ---------- Phase B: exact ranks + fm + scatter + P/Q (32 j/block, 8 lanes/j) ----------
__device__ inline float phaseB(int tid, int bid, const unsigned* __restrict__ ENC,
    float* __restrict__ SF2, int* __restrict__ PERM,
    float* __restrict__ PS, float* __restrict__ QS, float* __restrict__ FMf,
    unsigned* __restrict__ ks)
{
    const uint4* E4 = (const uint4*)ENC;
    uint4* K4 = (uint4*)ks;
    uint4 kv[8];
    unsigned mx = 0;
#pragma unroll
    for (int q = 0; q < 8; ++q) {
        kv[q] = E4[q * 256 + tid];
        mx = max(max(mx, kv[q].x), max(max(kv[q].y, kv[q].z), kv[q].w));
    }
#pragma unroll
    for (int m = 32; m >= 1; m >>= 1)
        mx = max(mx, (unsigned)__shfl_xor((int)mx, m, 64));
    if ((tid & 63) == 0) ks[tid >> 6] = mx;     // 4-word scratch
    __syncthreads();
    const unsigned gmx = max(max(ks[0], ks[1]), max(ks[2], ks[3]));
    const float fm = dec_f32(gmx);
    __syncthreads();
#pragma unroll
    for (int q = 0; q < 8; ++q) K4[q * 256 + tid] = kv[q];
    __syncthreads();

    const int jj = tid >> 3, s = tid & 7;       // 32 j's x 8 slices of 1024
    const int j = bid * 32 + jj;
    const unsigned th = ks[j];
    unsigned cnt = 0;
    for (int q = 0; q < 256; ++q) {
        const int qq = (q + s * 37) & 255;      // odd rotate -> distinct banks per s
        uint4 v = K4[s * 256 + qq];
        const int idx = s * 1024 + qq * 4;      // original element index
        const bool eq = (v.x == th) | (v.y == th) | (v.z == th) | (v.w == th);
        if (__builtin_expect(__any(eq), 0)) {   // rare exact tie-break
            cnt += (unsigned)((v.x < th) | ((v.x == th) & ((idx + 0) < j)));
            cnt += (unsigned)((v.y < th) | ((v.y == th) & ((idx + 1) < j)));
            cnt += (unsigned)((v.z < th) | ((v.z == th) & ((idx + 2) < j)));
            cnt += (unsigned)((v.w < th) | ((v.w == th) & ((idx + 3) < j)));
        } else {
            cnt += (unsigned)(v.x < th) + (unsigned)(v.y < th)
                 + (unsigned)(v.z < th) + (unsigned)(v.w < th);
        }
    }
#pragma unroll
    for (int m = 1; m < 8; m <<= 1)
        cnt += (unsigned)__shfl_xor((int)cnt, m, 64);
    if (s == 0) {
        const unsigned r = cnt;
        const float f = dec_f32(th);
        const float d = f - fm;
        SF2[r] = f;
        PERM[r] = j;
        PS[r] = expf(d);
        QS[r] = expf(ALPHA * d);
    }
    if (bid == 0 && tid == 0) FMf[0] = fm;
    return fm;
}

// ---------- Phase C: chunk sums + in-LDS scan (blocks 0..64 only) ----------
__device__ inline void phaseC(int tid, int cb,
    const float* __restrict__ H, const int* __restrict__ PERM,
    const float* __restrict__ PS, const float* __restrict__ QS,
    float* __restrict__ CHP, float* __restrict__ CHQ,
    float* __restrict__ chp, float* __restrict__ chq,
    float* __restrict__ sP, float* __restrict__ sQ)
{
    const int t = tid;
    float accP = 0.f, accQ = 0.f;
    if (cb < 64) {
        const int4*   P4 = (const int4*)(PERM + t * 32);
        const float4* S4 = (const float4*)(PS + t * 32);
        const float4* Q4 = (const float4*)(QS + t * 32);
#pragma unroll
        for (int q = 0; q < 8; ++q) {
            int4 jv = P4[q]; float4 pv = S4[q]; float4 qv = Q4[q];
            accP = fmaf(pv.x, H[jv.x * 64 + cb], accP); accQ = fmaf(qv.x, H[jv.x * 64 + cb], accQ);
            accP = fmaf(pv.y, H[jv.y * 64 + cb], accP); accQ = fmaf(qv.y, H[jv.y * 64 + cb], accQ);
            accP = fmaf(pv.z, H[jv.z * 64 + cb], accP); accQ = fmaf(qv.z, H[jv.z * 64 + cb], accQ);
            accP = fmaf(pv.w, H[jv.w * 64 + cb], accP); accQ = fmaf(qv.w, H[jv.w * 64 + cb], accQ);
        }
    } else {
        const float4* S4 = (const float4*)(PS + t * 32);
        const float4* Q4 = (const float4*)(QS + t * 32);
#pragma unroll
        for (int q = 0; q < 8; ++q) {
            float4 pv = S4[q]; float4 qv = Q4[q];
            accP += pv.x + pv.y + pv.z + pv.w;
            accQ += qv.x + qv.y + qv.z + qv.w;
        }
    }
    sP[t] = accP; sQ[t] = accQ;
    __syncthreads();
    for (int off = 1; off < 256; off <<= 1) {
        float uP = (t >= off) ? sP[t - off] : 0.f;
        float uQ = (t >= off) ? sQ[t - off] : 0.f;
        __syncthreads();
        sP[t] += uP; sQ[t] += uQ;
        __syncthreads();
    }
    const float eP = (t > 0) ? sP[t - 1] : 0.f;
    const float eQ = (t > 0) ? sQ[t - 1] : 0.f;
    if (cb < 64) {
        CHP[t * 64 + cb] = eP;
        CHQ[t * 64 + cb] = eQ;
        if (t == 255) { CHP[256 * 64 + cb] = sP[255]; CHQ[256 * 64 + cb] = sQ[255]; }
    } else {
        chp[t] = eP;
        chq[t] = eQ;
        if (t == 255) { chp[256] = sP[255]; chq[256] = sQ[255]; }
    }
}

// ---------- Phase D: per-row bsearch + 32-elem exact correction + elu (32 rows/block) ----------
__device__ inline void phaseD(int tid, int bid, float fm,
    const float* __restrict__ H, const float* __restrict__ F1,
    const float* __restrict__ SF2, const int* __restrict__ PERM,
    const float* __restrict__ PS, const float* __restrict__ QS,
    const float* __restrict__ CHP, const float* __restrict__ CHQ,
    const float* __restrict__ chp, const float* __restrict__ chq,
    float* __restrict__ OUT, float* __restrict__ sb)
{
    const int w = tid >> 6, c = tid & 63;
    sb[tid] = SF2[tid * 32];                  // chunk-start table (1 KB)
    __syncthreads();
    const float Ptot = CHP[256 * 64 + c];
    const float ptot = chp[256];
    for (int rr = 0; rr < 8; ++rr) {
        const int i = bid * 32 + w * 8 + rr;
        const float f1 = F1[i];
        const float s = f1 + fm;
        const float mrow = fmaxf(s, ALPHA * s);
        const float A = expf(s - mrow);
        const float B = expf(ALPHA * s - mrow);
        const float th = -f1;

        int lo = 0, hi = 256;
        while (lo < hi) { int mid = (lo + hi) >> 1; if (sb[mid] < th) lo = mid + 1; else hi = mid; }
        const int b = lo > 0 ? lo - 1 : 0;
        const int t0 = b * 32;

        float qv = CHQ[b * 64 + c], pp = CHP[b * 64 + c];
        float qs = chq[b],          ps = chp[b];
        const float4* SV4 = (const float4*)(SF2 + t0);
        const int4*   PJ4 = (const int4*)(PERM + t0);
        const float4* PP4 = (const float4*)(PS + t0);
        const float4* QQ4 = (const float4*)(QS + t0);
#pragma unroll
        for (int q = 0; q < 8; ++q) {
            float4 sv = SV4[q]; int4 jv = PJ4[q]; float4 Pv = PP4[q]; float4 Qv = QQ4[q];
            { const bool cd = sv.x < th; const float cq = cd ? Qv.x : 0.f, cp = cd ? Pv.x : 0.f;
              const float hv = H[jv.x * 64 + c]; qv = fmaf(cq, hv, qv); pp = fmaf(cp, hv, pp); qs += cq; ps += cp; }
            { const bool cd = sv.y < th; const float cq = cd ? Qv.y : 0.f, cp = cd ? Pv.y : 0.f;
              const float hv = H[jv.y * 64 + c]; qv = fmaf(cq, hv, qv); pp = fmaf(cp, hv, pp); qs += cq; ps += cp; }
            { const bool cd = sv.z < th; const float cq = cd ? Qv.z : 0.f, cp = cd ? Pv.z : 0.f;
              const float hv = H[jv.z * 64 + c]; qv = fmaf(cq, hv, qv); pp = fmaf(cp, hv, pp); qs += cq; ps += cp; }
            { const bool cd = sv.w < th; const float cq = cd ? Qv.w : 0.f, cp = cd ? Pv.w : 0.f;
              const float hv = H[jv.w * 64 + c]; qv = fmaf(cq, hv, qv); pp = fmaf(cp, hv, pp); qs += cq; ps += cp; }
        }
        const float Pvec = Ptot - pp;
        const float pden = ptot - ps;
        const float num = A * Pvec + B * qv;
        const float den = A * pden + B * qs;
        const float feat = num / den;
        OUT[i * 64 + c] = feat > 0.f ? feat : expm1f(feat);
    }
}

// ---------- Fused persistent kernel (256 blocks => unrejectable coop launch) ----------
__global__ __launch_bounds__(256) void fused(
    const float* __restrict__ X, const float* __restrict__ W, const float* __restrict__ aa,
    unsigned* __restrict__ BAR,
    float* __restrict__ H, float* __restrict__ F1, unsigned* __restrict__ ENC,
    float* __restrict__ FMf, float* __restrict__ SF2, int* __restrict__ PERM,
    float* __restrict__ PS, float* __restrict__ QS,
    float* __restrict__ CHP, float* __restrict__ CHQ,
    float* __restrict__ chp, float* __restrict__ chq, float* __restrict__ OUT)
{
    __shared__ union {
        struct { float xs[32 * 128]; float part[32 * 4 * 64]; } a;   // 49152 B
        unsigned ks[NR];                                             // 32768 B
        struct { float sP[256], sQ[256]; } c;                        // 2048 B
        float sb[256];                                               // 1024 B
    } u;
    const int tid = threadIdx.x;
    const int bid = blockIdx.x;

    phaseA(tid, bid, X, W, aa, H, F1, ENC, u.a.xs, u.a.part);
    gbar(BAR, NB);
    const float fm = phaseB(tid, bid, ENC, SF2, PERM, PS, QS, FMf, u.ks);
    gbar(BAR, 2 * NB);
    if (bid <= 64) phaseC(tid, bid, H, PERM, PS, QS, CHP, CHQ, chp, chq, u.c.sP, u.c.sQ);
    gbar(BAR, 3 * NB);
    phaseD(tid, bid, fm, H, F1, SF2, PERM, PS, QS, CHP, CHQ, chp, chq, OUT, u.sb);
}

// ---------- Fallback pipeline (same phase functions, 4 dispatches) ----------
__global__ __launch_bounds__(256) void k1_gemm(
    const float* __restrict__ X, const float* __restrict__ W, const float* __restrict__ aa,
    float* __restrict__ H, float* __restrict__ F1, unsigned* __restrict__ ENC)
{
    __shared__ float xs[32 * 128];
    __shared__ float part[32 * 4 * 64];
    phaseA(threadIdx.x, blockIdx.x, X, W, aa, H, F1, ENC, xs, part);
}
__global__ __launch_bounds__(256) void k2_rank(
    const unsigned* __restrict__ ENC, float* __restrict__ SF2, int* __restrict__ PERM,
    float* __restrict__ PS, float* __restrict__ QS, float* __restrict__ FMf)
{
    __shared__ unsigned ks[NR];
    phaseB(threadIdx.x, blockIdx.x, ENC, SF2, PERM, PS, QS, FMf, ks);
}
__global__ __launch_bounds__(256) void k34_chunkscan(
    const float* __restrict__ H, const int* __restrict__ PERM,
    const float* __restrict__ PS, const float* __restrict__ QS,
    float* __restrict__ CHP, float* __restrict__ CHQ,
    float* __restrict__ chp, float* __restrict__ chq)
{
    __shared__ float sP[256], sQ[256];
    phaseC(threadIdx.x, blockIdx.x, H, PERM, PS, QS, CHP, CHQ, chp, chq, sP, sQ);
}
__global__ __launch_bounds__(256) void k6_rows(
    const float* __restrict__ H, const float* __restrict__ F1, const float* __restrict__ FMf,
    const float* __restrict__ SF2, const int* __restrict__ PERM,
    const float* __restrict__ PS, const float* __restrict__ QS,
    const float* __restrict__ CHP, const float* __restrict__ CHQ,
    const float* __restrict__ chp, const float* __restrict__ chq, float* __restrict__ OUT)
{
    __shared__ float sb[256];
    phaseD(threadIdx.x, blockIdx.x, FMf[0], H, F1, SF2, PERM, PS, QS, CHP, CHQ, chp, chq, OUT, sb);
}

extern "C" void kernel_launch(void* const* d_in, const int* in_sizes, int n_in,
                              void* d_out, int out_size, void* d_ws, size_t ws_size,
                              hipStream_t stream) {
    const float* X = (const float*)d_in[0];   // 8192 x 128
    const float* W = (const float*)d_in[1];   // 128 x 64
    const float* a = (const float*)d_in[2];   // 128 x 1
    float* OUT = (float*)d_out;               // 8192 x 64

    unsigned* BAR = (unsigned*)d_ws;             // 16 (1 used) — memset each call
    float*    H    = (float*)d_ws + 16;          // 524288
    float*    F1   = H + 524288;                 // 8192
    unsigned* ENC  = (unsigned*)(F1 + 8192);     // 8192
    float*    FMf  = (float*)(ENC + 8192);       // 16 (1 used)
    float*    SF2  = FMf + 16;                   // 8192
    int*      PERM = (int*)(SF2 + 8192);         // 8192
    float*    PS   = (float*)(PERM + 8192);      // 8192
    float*    QS   = PS + 8192;                  // 8192
    float*    CHP  = QS + 8192;                  // 257*64
    float*    CHQ  = CHP + 257 * 64;             // 257*64
    float*    chp  = CHQ + 257 * 64;             // 257
    float*    chq  = chp + 257;                  // 257

    hipMemsetAsync(BAR, 0, 64, stream);
    void* args[] = { &X, &W, &a, &BAR, &H, &F1, &ENC, &FMf, &SF2, &PERM,
                     &PS, &QS, &CHP, &CHQ, &chp, &chq, &OUT };
    hipError_t err = hipLaunchCooperativeKernel((const void*)fused, dim3(NB), dim3(256),
                                                args, 0, stream);
    if (err != hipSuccess) {
        // Coop launch rejected: run the identical phases as 4 ordinary dispatches.
        k1_gemm<<<NB, 256, 0, stream>>>(X, W, a, H, F1, ENC);
        k2_rank<<<NB, 256, 0, stream>>>(ENC, SF2, PERM, PS, QS, FMf);
        k34_chunkscan<<<65, 256, 0, stream>>>(H, PERM, PS, QS, CHP, CHQ, chp, chq);
        k6_rows<<<NB, 256, 0, stream>>>(H, F1, FMf, SF2, PERM, PS, QS, CHP, CHQ, chp, chq, OUT);
    }
}

// Round 10
// 58.993 us; speedup vs baseline: 2.6917x; 2.6917x over previous
//
#include <hip/hip_runtime.h>

#define NR    8192
#define ALPHA 0.2f

__device__ inline unsigned enc_f32(float f) {
    unsigned u = __float_as_uint(f);
    return (u & 0x80000000u) ? ~u : (u | 0x80000000u);
}
__device__ inline float dec_f32(unsigned u) {
    return __uint_as_float((u & 0x80000000u) ? (u ^ 0x80000000u) : ~u);
}

// kA: H = X@W, f1, f2->enc key. 512 blocks x 16 rows. X read via wave-uniform
// addresses (scalar cache path), W in 32 VGPRs, k-split over 4 waves + part LDS.
__global__ __launch_bounds__(256) void kA(
    const float* __restrict__ X, const float* __restrict__ W, const float* __restrict__ aa,
    float* __restrict__ H, float* __restrict__ F1, unsigned* __restrict__ ENC)
{
    __shared__ float part[16 * 4 * 64];   // 16 KB
    const int tid = threadIdx.x, w = tid >> 6, c = tid & 63;
    const int R0 = blockIdx.x * 16;

    float Wreg[32];
#pragma unroll
    for (int e = 0; e < 32; ++e) Wreg[e] = W[(w * 32 + e) * 64 + c];

    for (int r = 0; r < 16; ++r) {
        const float* xr = X + (R0 + r) * 128 + w * 32;   // wave-uniform address
        float acc = 0.f;
#pragma unroll
        for (int e = 0; e < 32; ++e) acc = fmaf(xr[e], Wreg[e], acc);
        part[(r * 4 + w) * 64 + c] = acc;
    }
    __syncthreads();

    const float a1 = aa[c], a2 = aa[64 + c];
    for (int rr = 0; rr < 4; ++rr) {
        const int r = w * 4 + rr, i = R0 + r;
        float h = part[(r * 4 + 0) * 64 + c] + part[(r * 4 + 1) * 64 + c]
                + part[(r * 4 + 2) * 64 + c] + part[(r * 4 + 3) * 64 + c];
        H[i * 64 + c] = h;
        float v1 = h * a1, v2 = h * a2;
#pragma unroll
        for (int m = 32; m >= 1; m >>= 1) {
            v1 += __shfl_xor(v1, m, 64);
            v2 += __shfl_xor(v2, m, 64);
        }
        if (c == 0) { F1[i] = v1; ENC[i] = enc_f32(v2); }
    }
}

// kB: exact ranks via 64-bit tie-embedded sortkeys, all in registers.
// 512 blocks x 16 j's. Each thread: 32 keys (key<<13|idx); 16 thresholds
// (SGPR); strict u64 compare = exact tie-broken rank. Shuffle+LDS reduce.
__global__ __launch_bounds__(256) void kB(
    const unsigned* __restrict__ ENC, float* __restrict__ SF2, int* __restrict__ PERM)
{
    __shared__ unsigned cw[4 * 16];
    const int tid = threadIdx.x, bid = blockIdx.x;
    const uint4* E4 = (const uint4*)ENC;

    unsigned long long k64[32];
    {
        const unsigned base = tid * 4;
#pragma unroll
        for (int q = 0; q < 8; ++q) {
            uint4 v = E4[q * 256 + tid];
            const unsigned ib = q * 1024 + base;
            k64[q * 4 + 0] = ((unsigned long long)v.x << 13) | (ib + 0);
            k64[q * 4 + 1] = ((unsigned long long)v.y << 13) | (ib + 1);
            k64[q * 4 + 2] = ((unsigned long long)v.z << 13) | (ib + 2);
            k64[q * 4 + 3] = ((unsigned long long)v.w << 13) | (ib + 3);
        }
    }

    unsigned cnt[16];
#pragma unroll
    for (int jj = 0; jj < 16; ++jj) {
        const int j = bid * 16 + jj;
        const unsigned long long th = ((unsigned long long)ENC[j] << 13) | (unsigned)j;
        unsigned cjj = 0;
#pragma unroll
        for (int q = 0; q < 32; ++q) cjj += (unsigned)(k64[q] < th);
        cnt[jj] = cjj;
    }
#pragma unroll
    for (int jj = 0; jj < 16; ++jj) {
        unsigned v = cnt[jj];
#pragma unroll
        for (int m = 32; m >= 1; m >>= 1) v += (unsigned)__shfl_xor((int)v, m, 64);
        cnt[jj] = v;
    }
    const int w = tid >> 6;
    if ((tid & 63) == 0) {
#pragma unroll
        for (int jj = 0; jj < 16; ++jj) cw[w * 16 + jj] = cnt[jj];
    }
    __syncthreads();
    if (tid < 16) {
        const unsigned r = cw[tid] + cw[16 + tid] + cw[32 + tid] + cw[48 + tid];
        const int j = bid * 16 + tid;
        SF2[r] = dec_f32(ENC[j]);
        PERM[r] = j;
    }
}

// kC34: chunk sums + in-LDS scan, 65 blocks. Block cb<64 owns output column cb
// (on-the-fly P/Q exp); block 64 owns the scalar sums AND materializes PS/QS/cs.
// Arrays stride 65: column 64 = scalar. One scan covers vectors and scalars.
__global__ __launch_bounds__(256) void kC34(
    const float* __restrict__ H, const float* __restrict__ SF2, const int* __restrict__ PERM,
    float* __restrict__ PS, float* __restrict__ QS,
    float* __restrict__ CHPx, float* __restrict__ CHQx, float* __restrict__ cs)
{
    __shared__ float sP[256], sQ[256];
    const int t = threadIdx.x, cb = blockIdx.x;
    const float fm = SF2[NR - 1];
    float accP = 0.f, accQ = 0.f;

    if (cb < 64) {
        const float4* S4 = (const float4*)(SF2 + t * 32);
        const int4*   P4 = (const int4*)(PERM + t * 32);
#pragma unroll
        for (int q = 0; q < 8; ++q) {
            float4 f = S4[q]; int4 jv = P4[q];
            { const float d = f.x - fm; const float P = expf(d), Q = expf(ALPHA * d);
              const float hv = H[jv.x * 64 + cb]; accP = fmaf(P, hv, accP); accQ = fmaf(Q, hv, accQ); }
            { const float d = f.y - fm; const float P = expf(d), Q = expf(ALPHA * d);
              const float hv = H[jv.y * 64 + cb]; accP = fmaf(P, hv, accP); accQ = fmaf(Q, hv, accQ); }
            { const float d = f.z - fm; const float P = expf(d), Q = expf(ALPHA * d);
              const float hv = H[jv.z * 64 + cb]; accP = fmaf(P, hv, accP); accQ = fmaf(Q, hv, accQ); }
            { const float d = f.w - fm; const float P = expf(d), Q = expf(ALPHA * d);
              const float hv = H[jv.w * 64 + cb]; accP = fmaf(P, hv, accP); accQ = fmaf(Q, hv, accQ); }
        }
    } else {
        const float4* S4 = (const float4*)(SF2 + t * 32);
        float4* PS4 = (float4*)(PS + t * 32);
        float4* QS4 = (float4*)(QS + t * 32);
#pragma unroll
        for (int q = 0; q < 8; ++q) {
            float4 f = S4[q];
            const float d0 = f.x - fm, d1 = f.y - fm, d2 = f.z - fm, d3 = f.w - fm;
            const float p0 = expf(d0), p1 = expf(d1), p2 = expf(d2), p3 = expf(d3);
            const float q0 = expf(ALPHA * d0), q1 = expf(ALPHA * d1);
            const float q2 = expf(ALPHA * d2), q3 = expf(ALPHA * d3);
            PS4[q] = make_float4(p0, p1, p2, p3);
            QS4[q] = make_float4(q0, q1, q2, q3);
            accP += p0 + p1 + p2 + p3;
            accQ += q0 + q1 + q2 + q3;
        }
        cs[t] = SF2[t * 32];
    }

    sP[t] = accP; sQ[t] = accQ;
    __syncthreads();
    for (int off = 1; off < 256; off <<= 1) {
        float uP = (t >= off) ? sP[t - off] : 0.f;
        float uQ = (t >= off) ? sQ[t - off] : 0.f;
        __syncthreads();
        sP[t] += uP; sQ[t] += uQ;
        __syncthreads();
    }
    const float eP = (t > 0) ? sP[t - 1] : 0.f;
    const float eQ = (t > 0) ? sQ[t - 1] : 0.f;
    CHPx[t * 65 + cb] = eP;
    CHQx[t * 65 + cb] = eQ;
    if (t == 255) { CHPx[256 * 65 + cb] = sP[255]; CHQx[256 * 65 + cb] = sQ[255]; }
}

// kD: per-row coarse bsearch (cs in LDS) + 32-elem exact predicated correction
// + elu. 512 blocks x 16 rows; correction reads are wave-uniform (scalar path)
// except the coalesced H row loads.
__global__ __launch_bounds__(256) void kD(
    const float* __restrict__ H, const float* __restrict__ F1, const float* __restrict__ SF2,
    const int* __restrict__ PERM, const float* __restrict__ PS, const float* __restrict__ QS,
    const float* __restrict__ CHPx, const float* __restrict__ CHQx,
    const float* __restrict__ cs, float* __restrict__ OUT)
{
    __shared__ float sb[256];
    const int tid = threadIdx.x, w = tid >> 6, c = tid & 63, bid = blockIdx.x;
    sb[tid] = cs[tid];
    __syncthreads();
    const float fm = SF2[NR - 1];
    const float Ptot = CHPx[256 * 65 + c], ptot = CHPx[256 * 65 + 64];

    for (int rr = 0; rr < 4; ++rr) {
        const int i = bid * 16 + w * 4 + rr;
        const float f1 = F1[i];
        const float s = f1 + fm;
        const float mrow = fmaxf(s, ALPHA * s);
        const float A = expf(s - mrow);
        const float B = expf(ALPHA * s - mrow);
        const float th = -f1;

        int lo = 0, hi = 256;
        while (lo < hi) { int mid = (lo + hi) >> 1; if (sb[mid] < th) lo = mid + 1; else hi = mid; }
        const int b = lo > 0 ? lo - 1 : 0;
        const int t0 = b * 32;

        float qv = CHQx[b * 65 + c],  pp = CHPx[b * 65 + c];
        float qs = CHQx[b * 65 + 64], ps = CHPx[b * 65 + 64];
        for (int tt = 0; tt < 32; ++tt) {
            const float sv = SF2[t0 + tt];      // wave-uniform
            const int jx = PERM[t0 + tt];       // wave-uniform
            const float P = PS[t0 + tt], Q = QS[t0 + tt];
            const float hv = H[jx * 64 + c];    // coalesced 256B row
            const bool cd = sv < th;
            const float cQ = cd ? Q : 0.f, cP = cd ? P : 0.f;
            qv = fmaf(cQ, hv, qv); qs += cQ;
            pp = fmaf(cP, hv, pp); ps += cP;
        }
        const float Pvec = Ptot - pp;
        const float pden = ptot - ps;
        const float num = A * Pvec + B * qv;
        const float den = A * pden + B * qs;
        const float feat = num / den;
        OUT[i * 64 + c] = feat > 0.f ? feat : expm1f(feat);
    }
}

extern "C" void kernel_launch(void* const* d_in, const int* in_sizes, int n_in,
                              void* d_out, int out_size, void* d_ws, size_t ws_size,
                              hipStream_t stream) {
    const float* X = (const float*)d_in[0];   // 8192 x 128
    const float* W = (const float*)d_in[1];   // 128 x 64
    const float* a = (const float*)d_in[2];   // 128 x 1
    float* OUT = (float*)d_out;               // 8192 x 64

    float*    ws   = (float*)d_ws;
    float*    H    = ws;                         // 524288
    float*    F1   = H + 524288;                 // 8192
    unsigned* ENC  = (unsigned*)(F1 + 8192);     // 8192
    float*    SF2  = (float*)(ENC + 8192);       // 8192
    int*      PERM = (int*)(SF2 + 8192);         // 8192
    float*    PS   = (float*)(PERM + 8192);      // 8192
    float*    QS   = PS + 8192;                  // 8192
    float*    CHPx = QS + 8192;                  // 257*65
    float*    CHQx = CHPx + 257 * 65;            // 257*65
    float*    cs   = CHQx + 257 * 65;            // 256

    kA  <<<512, 256, 0, stream>>>(X, W, a, H, F1, ENC);
    kB  <<<512, 256, 0, stream>>>(ENC, SF2, PERM);
    kC34<<< 65, 256, 0, stream>>>(H, SF2, PERM, PS, QS, CHPx, CHQx, cs);
    kD  <<<512, 256, 0, stream>>>(H, F1, SF2, PERM, PS, QS, CHPx, CHQx, cs, OUT);
}

// Round 11
// 42.473 us; speedup vs baseline: 3.7386x; 1.3889x over previous
//
#include <hip/hip_runtime.h>

#define NR    8192
#define ALPHA 0.2f
#define NCH   512          // chunks
#define CSZ   16           // elements per chunk

__device__ inline unsigned enc_f32(float f) {
    unsigned u = __float_as_uint(f);
    return (u & 0x80000000u) ? ~u : (u | 0x80000000u);
}
__device__ inline float dec_f32(unsigned u) {
    return __uint_as_float((u & 0x80000000u) ? (u ^ 0x80000000u) : ~u);
}

// kA: H = X@W, f1, f2->enc key. 512 blocks x 16 rows. float4-staged X,
// W in 32 VGPRs, k-split over 4 waves, part LDS reduce.
__global__ __launch_bounds__(256) void kA(
    const float* __restrict__ X, const float* __restrict__ W, const float* __restrict__ aa,
    float* __restrict__ H, float* __restrict__ F1, unsigned* __restrict__ ENC)
{
    __shared__ __align__(16) float xs[16 * 128];   // 8 KB
    __shared__ float part[16 * 4 * 64];            // 16 KB
    const int tid = threadIdx.x, w = tid >> 6, c = tid & 63;
    const int R0 = blockIdx.x * 16;

    float Wreg[32];
#pragma unroll
    for (int e = 0; e < 32; ++e) Wreg[e] = W[(w * 32 + e) * 64 + c];
    {
        const float4* X4 = (const float4*)(X + R0 * 128);
        float4* xs4 = (float4*)xs;
        xs4[tid] = X4[tid];
        xs4[256 + tid] = X4[256 + tid];
    }
    __syncthreads();

    for (int r = 0; r < 16; ++r) {
        const float4* xr4 = (const float4*)&xs[r * 128 + w * 32];
        float acc = 0.f;
#pragma unroll
        for (int e = 0; e < 8; ++e) {
            float4 xv = xr4[e];
            acc = fmaf(xv.x, Wreg[e * 4 + 0], acc);
            acc = fmaf(xv.y, Wreg[e * 4 + 1], acc);
            acc = fmaf(xv.z, Wreg[e * 4 + 2], acc);
            acc = fmaf(xv.w, Wreg[e * 4 + 3], acc);
        }
        part[(r * 4 + w) * 64 + c] = acc;
    }
    __syncthreads();

    const float a1 = aa[c], a2 = aa[64 + c];
    for (int rr = 0; rr < 4; ++rr) {
        const int r = w * 4 + rr, i = R0 + r;
        float h = part[(r * 4 + 0) * 64 + c] + part[(r * 4 + 1) * 64 + c]
                + part[(r * 4 + 2) * 64 + c] + part[(r * 4 + 3) * 64 + c];
        H[i * 64 + c] = h;
        float v1 = h * a1, v2 = h * a2;
#pragma unroll
        for (int m = 32; m >= 1; m >>= 1) {
            v1 += __shfl_xor(v1, m, 64);
            v2 += __shfl_xor(v2, m, 64);
        }
        if (c == 0) { F1[i] = v1; ENC[i] = enc_f32(v2); }
    }
}

// kB: exact tie-broken ranks via 64-bit sortkeys (enc<<13|idx), registers only.
// 1024 blocks x 8 j's. Thresholds block-uniform (scalar path). 32 keys/thread.
__global__ __launch_bounds__(256) void kB(
    const unsigned* __restrict__ ENC, float* __restrict__ SF2, int* __restrict__ PERM)
{
    __shared__ unsigned cw[4 * 8];
    const int tid = threadIdx.x, bid = blockIdx.x;
    const uint4* E4 = (const uint4*)ENC;

    unsigned long long k64[32];
    {
        const unsigned base = tid * 4;
#pragma unroll
        for (int q = 0; q < 8; ++q) {
            uint4 v = E4[q * 256 + tid];
            const unsigned ib = q * 1024 + base;
            k64[q * 4 + 0] = ((unsigned long long)v.x << 13) | (ib + 0);
            k64[q * 4 + 1] = ((unsigned long long)v.y << 13) | (ib + 1);
            k64[q * 4 + 2] = ((unsigned long long)v.z << 13) | (ib + 2);
            k64[q * 4 + 3] = ((unsigned long long)v.w << 13) | (ib + 3);
        }
    }

    unsigned cnt[8];
#pragma unroll
    for (int jj = 0; jj < 8; ++jj) {
        const int j = bid * 8 + jj;                          // block-uniform
        const unsigned long long th = ((unsigned long long)ENC[j] << 13) | (unsigned)j;
        unsigned cjj = 0;
#pragma unroll
        for (int q = 0; q < 32; ++q) cjj += (unsigned)(k64[q] < th);
        cnt[jj] = cjj;
    }
#pragma unroll
    for (int jj = 0; jj < 8; ++jj) {
        unsigned v = cnt[jj];
#pragma unroll
        for (int m = 32; m >= 1; m >>= 1) v += (unsigned)__shfl_xor((int)v, m, 64);
        cnt[jj] = v;
    }
    const int w = tid >> 6;
    if ((tid & 63) == 0) {
#pragma unroll
        for (int jj = 0; jj < 8; ++jj) cw[w * 8 + jj] = cnt[jj];
    }
    __syncthreads();
    if (tid < 8) {
        const unsigned r = cw[tid] + cw[8 + tid] + cw[16 + tid] + cw[24 + tid];
        const int j = bid * 8 + tid;
        SF2[r] = dec_f32(ENC[j]);
        PERM[r] = j;
    }
}

// kC34: chunk sums (512 chunks x 16) + in-LDS scan. 65 blocks x 1024 threads
// (4x waves for the latency-bound gathers). Block cb<64 owns output column cb;
// block 64 owns scalar sums AND packs SPQJ float4 (sf2,P,Q,perm) + cs table.
__global__ __launch_bounds__(1024) void kC34(
    const float* __restrict__ H, const float* __restrict__ SF2, const int* __restrict__ PERM,
    float4* __restrict__ SPQJ, float* __restrict__ CHPx, float* __restrict__ CHQx,
    float* __restrict__ cs)
{
    __shared__ float preP[1024], preQ[1024];
    __shared__ float scP[NCH], scQ[NCH];
    const int t = threadIdx.x, cb = blockIdx.x;
    const float fm = SF2[NR - 1];
    float accP = 0.f, accQ = 0.f;

    const float4* S4 = (const float4*)(SF2 + t * 8);
    const int4*   P4 = (const int4*)(PERM + t * 8);
    float4 f0 = S4[0], f1v = S4[1];
    int4   j0 = P4[0], j1 = P4[1];
    float sv[8] = { f0.x, f0.y, f0.z, f0.w, f1v.x, f1v.y, f1v.z, f1v.w };
    int   jx[8] = { j0.x, j0.y, j0.z, j0.w, j1.x, j1.y, j1.z, j1.w };

    if (cb < 64) {
#pragma unroll
        for (int e = 0; e < 8; ++e) {
            const float d = sv[e] - fm;
            const float P = __expf(d), Q = __expf(ALPHA * d);
            const float hv = H[jx[e] * 64 + cb];
            accP = fmaf(P, hv, accP);
            accQ = fmaf(Q, hv, accQ);
        }
    } else {
#pragma unroll
        for (int e = 0; e < 8; ++e) {
            const float d = sv[e] - fm;
            const float P = __expf(d), Q = __expf(ALPHA * d);
            SPQJ[t * 8 + e] = make_float4(sv[e], P, Q, __int_as_float(jx[e]));
            accP += P; accQ += Q;
        }
        if (t < NCH) cs[t] = SF2[t * CSZ];
    }

    preP[t] = accP; preQ[t] = accQ;
    __syncthreads();
    float vP = 0.f, vQ = 0.f;
    if (t < NCH) {                       // chunk t = threads 2t, 2t+1
        vP = preP[2 * t] + preP[2 * t + 1];
        vQ = preQ[2 * t] + preQ[2 * t + 1];
        scP[t] = vP; scQ[t] = vQ;
    }
    __syncthreads();
    for (int off = 1; off < NCH; off <<= 1) {
        float uP = 0.f, uQ = 0.f;
        if (t < NCH && t >= off) { uP = scP[t - off]; uQ = scQ[t - off]; }
        __syncthreads();
        if (t < NCH) { scP[t] += uP; scQ[t] += uQ; }
        __syncthreads();
    }
    if (t < NCH) {
        const float eP = (t > 0) ? scP[t - 1] : 0.f;     // exclusive
        const float eQ = (t > 0) ? scQ[t - 1] : 0.f;
        CHPx[t * 65 + cb] = eP;
        CHQx[t * 65 + cb] = eQ;
        if (t == NCH - 1) { CHPx[NCH * 65 + cb] = scP[t]; CHQx[NCH * 65 + cb] = scQ[t]; }
    }
}

// kD: per-row bsearch (cs in LDS, 9 steps) + 16-elem exact predicated correction
// (one SPQJ float4 per element) + elu. 2048 blocks x 4 rows (1 row/wave).
__global__ __launch_bounds__(256) void kD(
    const float* __restrict__ H, const float* __restrict__ F1, const float* __restrict__ SF2,
    const float4* __restrict__ SPQJ, const float* __restrict__ CHPx,
    const float* __restrict__ CHQx, const float* __restrict__ cs, float* __restrict__ OUT)
{
    __shared__ float sb[NCH];
    const int tid = threadIdx.x, w = tid >> 6, c = tid & 63, bid = blockIdx.x;
    sb[tid] = cs[tid];
    sb[256 + tid] = cs[256 + tid];
    __syncthreads();

    const float fm = SF2[NR - 1];
    const float Ptot = CHPx[NCH * 65 + c], ptot = CHPx[NCH * 65 + 64];
    const int i = bid * 4 + w;

    const float f1 = F1[i];
    const float s = f1 + fm;
    const float mrow = fmaxf(s, ALPHA * s);
    const float A = __expf(s - mrow);
    const float B = __expf(ALPHA * s - mrow);
    const float th = -f1;

    int lo = 0, hi = NCH;
    while (lo < hi) { int mid = (lo + hi) >> 1; if (sb[mid] < th) lo = mid + 1; else hi = mid; }
    const int b = lo > 0 ? lo - 1 : 0;
    const int t0 = b * CSZ;

    float qv = CHQx[b * 65 + c],  pp = CHPx[b * 65 + c];
    float qs = CHQx[b * 65 + 64], ps = CHPx[b * 65 + 64];
#pragma unroll
    for (int tt = 0; tt < CSZ; ++tt) {
        const float4 v = SPQJ[t0 + tt];         // wave-uniform 16B broadcast
        const int jv = __float_as_int(v.w);
        const float hv = H[jv * 64 + c];        // coalesced 256B row
        const bool cd = v.x < th;
        const float cP = cd ? v.y : 0.f, cQ = cd ? v.z : 0.f;
        qv = fmaf(cQ, hv, qv); qs += cQ;
        pp = fmaf(cP, hv, pp); ps += cP;
    }
    const float Pvec = Ptot - pp;
    const float pden = ptot - ps;
    const float num = A * Pvec + B * qv;
    const float den = A * pden + B * qs;
    const float feat = num / den;
    OUT[i * 64 + c] = feat > 0.f ? feat : expm1f(feat);
}

extern "C" void kernel_launch(void* const* d_in, const int* in_sizes, int n_in,
                              void* d_out, int out_size, void* d_ws, size_t ws_size,
                              hipStream_t stream) {
    const float* X = (const float*)d_in[0];   // 8192 x 128
    const float* W = (const float*)d_in[1];   // 128 x 64
    const float* a = (const float*)d_in[2];   // 128 x 1
    float* OUT = (float*)d_out;               // 8192 x 64

    float*    ws   = (float*)d_ws;
    float*    H    = ws;                         // 524288
    float*    F1   = H + 524288;                 // 8192
    unsigned* ENC  = (unsigned*)(F1 + 8192);     // 8192
    float*    SF2  = (float*)(ENC + 8192);       // 8192
    int*      PERM = (int*)(SF2 + 8192);         // 8192
    float4*   SPQJ = (float4*)(PERM + 8192);     // 8192 float4 (16B-aligned)
    float*    CHPx = (float*)(SPQJ + 8192);      // 513*65
    float*    CHQx = CHPx + 513 * 65;            // 513*65
    float*    cs   = CHQx + 513 * 65;            // 512

    kA  <<<512,  256,  0, stream>>>(X, W, a, H, F1, ENC);
    kB  <<<1024, 256,  0, stream>>>(ENC, SF2, PERM);
    kC34<<<65,   1024, 0, stream>>>(H, SF2, PERM, SPQJ, CHPx, CHQx, cs);
    kD  <<<2048, 256,  0, stream>>>(H, F1, SF2, SPQJ, CHPx, CHQx, cs, OUT);
}